// Round 5
// baseline (67.507 us; speedup 1.0000x reference)
//
#include <hip/hip_runtime.h>

// ---------------------------------------------------------------------------
// EfficentLePE, block-local: block = (window w, head-pair g).
// Window = [128 rows x 8 cols] tokens; head h <-> channels [h*16,(h+1)*16).
//   A[h] = softmax_e( SCALE * sum_n K[n,d] V[n,e] )   (16x16)
//   out[n,e] = sum_d Q[n,d] A[h][d,e] + depthwise3x3(Q)[n,e] + bias
// Pass 1: K/V 32-ch slices, 8-row tiles, TRIPLE-buffered with counted
//   per-wave vmcnt + raw s_barrier (loads in flight across barriers),
//   8d x 4e register blocking -> shfl pre-reduce -> 8KB scratch.
// Pass 2: Q 16-row(+halo) tiles, dbuf, quad-XOR-swizzled LDS, Q.A + conv.
// LDS = 48 KB total. No workspace, no grid sync.
// ---------------------------------------------------------------------------

static constexpr int BB   = 8;
static constexpr int RES  = 128;
static constexpr int DIM  = 128;
static constexpr int WSP  = 8;
static constexpr int L    = RES * RES;   // 16384
static constexpr float SCALE = 0.25f;    // HD^-0.5, HD=16

#define GLD_LDS16(g, l)                                                        \
  __builtin_amdgcn_global_load_lds(                                            \
      (const __attribute__((address_space(1))) void*)(const void*)(g),         \
      (__attribute__((address_space(3))) void*)(l), 16, 0, 0)

__global__ __launch_bounds__(256, 2) void fused_lepe(
    const float* __restrict__ Qg, const float* __restrict__ Kg,
    const float* __restrict__ Vg, const float* __restrict__ cw,
    const float* __restrict__ cb, float* __restrict__ outp) {
  // smem map (floats), total 12288 = 48 KB:
  //  pass1: K triple [0,6144) (3 x 2048), V triple [6144,12288)
  //  pass2: Qbuf0 [0,4608), Qbuf1 [4608,9216)      (K/V dead by then)
  //  A_sm  [9216,9728)   (in V buf1 tail, written after last V read)
  //  scratch [10240,12288) = V buf2 (written after last compute)
  __shared__ float smem[12288];
  float* const A_sm    = smem + 9216;
  float* const scratch = smem + 10240;

  const int b  = blockIdx.x;            // 0..511
  const int w  = b >> 2, g = b & 3;     // window, head-group (2 heads)
  const int bi = w >> 4, wb = w & 15;   // batch, window-col
  const int t  = threadIdx.x;
  const int wave = t >> 6, lane = t & 63;
  const size_t win_base = (size_t)(bi * L + wb * WSP) * DIM;
  const int ch0 = g * 32;               // first global channel of this group

  // ======== Pass 1: Gram = K^T V, 16 tiles of 8 image rows ================
  // lane -> (token-split, cell-block): combo = lane&15 -> h1, dgrp(8d), eq(4e)
  const int combo = lane & 15;
  const int split = lane >> 4;
  const int h1 = combo >> 3, dgrp = (combo >> 2) & 1, eq = combo & 3;
  const int koff = h1 * 16 + dgrp * 8;
  const int voff = h1 * 16 + eq * 4;
  const int n0 = (wave * 4 + split) * 4;   // 4 tokens per lane per tile

  float4 acc[8];
#pragma unroll
  for (int i = 0; i < 8; ++i) acc[i] = make_float4(0.f, 0.f, 0.f, 0.f);

  auto stageKV = [&](int tile, int buf) {
    // 16 chunks (K rows 0..7, V rows 0..7), 4 per wave, 1KB each
    for (int c = wave; c < 16; c += 4) {
      const int mat = c >> 3, rr = c & 7;
      const float* src = (mat ? Vg : Kg) + win_base +
                         (size_t)(tile * 8 + rr) * (RES * DIM) +
                         (lane >> 3) * DIM + ch0 + (lane & 7) * 4;
      float* dst = smem + mat * 6144 + buf * 2048 + rr * 256;
      GLD_LDS16(src, dst);
    }
  };

  stageKV(0, 0);
  stageKV(1, 1);
  for (int tt = 0; tt < 16; ++tt) {
    // own stage(tt) landed (stage(tt+1)'s 4 loads may stay in flight)
    if (tt < 15) asm volatile("s_waitcnt vmcnt(4)" ::: "memory");
    else         asm volatile("s_waitcnt vmcnt(0)" ::: "memory");
    __builtin_amdgcn_s_barrier();      // all waves done with buf (tt+2)%3
    if (tt + 2 < 16) stageKV(tt + 2, (tt + 2) % 3);
    const float* Kb = smem + (tt % 3) * 2048;
    const float* Vb = smem + 6144 + (tt % 3) * 2048;
#pragma unroll
    for (int i = 0; i < 4; ++i) {
      const int n = n0 + i;
      const float4 k0 = *reinterpret_cast<const float4*>(&Kb[n * 32 + koff]);
      const float4 k1 = *reinterpret_cast<const float4*>(&Kb[n * 32 + koff + 4]);
      const float4 v  = *reinterpret_cast<const float4*>(&Vb[n * 32 + voff]);
#define FMA4(a, s)                                                             \
  a.x += (s) * v.x; a.y += (s) * v.y; a.z += (s) * v.z; a.w += (s) * v.w;
      FMA4(acc[0], k0.x) FMA4(acc[1], k0.y) FMA4(acc[2], k0.z) FMA4(acc[3], k0.w)
      FMA4(acc[4], k1.x) FMA4(acc[5], k1.y) FMA4(acc[6], k1.z) FMA4(acc[7], k1.w)
#undef FMA4
    }
  }

  // within-wave reduce over the 4 token-splits (lane bits 4,5)
#pragma unroll
  for (int i = 0; i < 8; ++i) {
    acc[i].x += __shfl_xor(acc[i].x, 16); acc[i].y += __shfl_xor(acc[i].y, 16);
    acc[i].z += __shfl_xor(acc[i].z, 16); acc[i].w += __shfl_xor(acc[i].w, 16);
    acc[i].x += __shfl_xor(acc[i].x, 32); acc[i].y += __shfl_xor(acc[i].y, 32);
    acc[i].z += __shfl_xor(acc[i].z, 32); acc[i].w += __shfl_xor(acc[i].w, 32);
  }
  if (lane < 16) {                       // scratch[wave][combo][8d*4e]
    float* sc = scratch + wave * 512 + combo * 32;
#pragma unroll
    for (int i = 0; i < 8; ++i)
      *reinterpret_cast<float4*>(&sc[i * 4]) = acc[i];
  }
  __syncthreads();                       // scratch visible; K/V bufs dead

  // ======== Q-tile staging (18 rows incl. halos, quad-XOR swizzled) =======
  auto stageQ = [&](int tile, int buf) {
    const int r0 = tile * 16;
    float* qb = smem + buf * 4608;
    for (int c = wave; c < 18; c += 4) {
      const int r = r0 - 1 + c;          // image row for buffer row c
      float* dst = qb + c * 256;
      if ((unsigned)r < 128u) {
        const float* src = Qg + win_base + (size_t)r * (RES * DIM) +
                           (lane >> 3) * DIM + ch0 +
                           (((lane & 7) ^ (c & 7)) << 2);
        GLD_LDS16(src, dst);
      } else {
        *reinterpret_cast<float4*>(dst + lane * 4) =
            make_float4(0.f, 0.f, 0.f, 0.f);
      }
    }
  };
  stageQ(0, 0);                          // latency hides under reduce below

  // ======== reduce 4 wave-copies + softmax over e -> A_sm[h*16+d][e] ======
  {
    const int r = t >> 3, e2 = t & 7;    // r = h*16+d, e in {2e2, 2e2+1}
    const int cmb = (r >> 4) * 8 + ((r >> 3) & 1) * 4 + (e2 >> 1);
    const float* s0 = scratch + cmb * 32 + (r & 7) * 4 + (e2 & 1) * 2;
    float v0 = (s0[0] + s0[512] + s0[1024] + s0[1536]) * SCALE;
    float v1 = (s0[1] + s0[513] + s0[1025] + s0[1537]) * SCALE;
    float m = fmaxf(v0, v1);
    m = fmaxf(m, __shfl_xor(m, 1));
    m = fmaxf(m, __shfl_xor(m, 2));
    m = fmaxf(m, __shfl_xor(m, 4));
    v0 = __expf(v0 - m); v1 = __expf(v1 - m);
    float ss = v0 + v1;
    ss += __shfl_xor(ss, 1);
    ss += __shfl_xor(ss, 2);
    ss += __shfl_xor(ss, 4);
    const float ri = 1.0f / ss;
    A_sm[r * 16 + e2 * 2 + 0] = v0 * ri;
    A_sm[r * 16 + e2 * 2 + 1] = v1 * ri;
  }
  __syncthreads();                       // A_sm ready; Q tile 0 drained

  // ======== Pass 2 setup: per-thread A column, conv weights, bias =========
  const int cq   = t & 7;                // channel quad (4 ch) within 32
  const int lr   = (t >> 3) & 15;        // local output row in tile
  const int half = t >> 7;               // wl range: half*4 .. half*4+3
  const int hg = cq >> 2, e0 = (cq & 3) * 4;
  const int cg = ch0 + cq * 4;           // global channel quad base

  float4 Acol[16];
#pragma unroll
  for (int d = 0; d < 16; ++d)
    Acol[d] = *reinterpret_cast<const float4*>(&A_sm[(hg * 16 + d) * 16 + e0]);
  float4 wgt[9];
#pragma unroll
  for (int tap = 0; tap < 9; ++tap) {
    wgt[tap].x = cw[(cg + 0) * 9 + tap];
    wgt[tap].y = cw[(cg + 1) * 9 + tap];
    wgt[tap].z = cw[(cg + 2) * 9 + tap];
    wgt[tap].w = cw[(cg + 3) * 9 + tap];
  }
  const float4 bias = *reinterpret_cast<const float4*>(&cb[cg]);
  const float4 zero4 = make_float4(0.f, 0.f, 0.f, 0.f);

#define ACC(qs, d)                                                             \
  o.x += (qs) * Acol[d].x; o.y += (qs) * Acol[d].y;                            \
  o.z += (qs) * Acol[d].z; o.w += (qs) * Acol[d].w;

  // ======== Pass 2 main loop: 8 tiles of 16 rows, double-buffered =========
  int buf = 0;
  for (int tile = 0; tile < 8; ++tile) {
    if (tile < 7) stageQ(tile + 1, buf ^ 1);
    const float* Qb = smem + buf * 4608;
    const int r0 = tile * 16;
    const int w0 = half * 4;

    float4 cL[3], cC[3], cR[3];
    auto ldcol = [&](int cidx, float4* dv) {
#pragma unroll
      for (int dy = 0; dy < 3; ++dy) {
        const int br = lr + dy;          // buffer row
        dv[dy] = ((unsigned)cidx < 8u)
                     ? *reinterpret_cast<const float4*>(
                           &Qb[(br * 8 + cidx) * 32 + ((cq ^ (br & 7)) << 2)])
                     : zero4;
      }
    };
    ldcol(w0 - 1, cL);
    ldcol(w0, cC);

#pragma unroll
    for (int k = 0; k < 4; ++k) {
      const int wl = w0 + k;
      ldcol(wl + 1, cR);
      float4 o = bias;
#pragma unroll
      for (int dy = 0; dy < 3; ++dy) {
        const int t0 = dy * 3;
        o.x += cL[dy].x * wgt[t0].x + cC[dy].x * wgt[t0+1].x + cR[dy].x * wgt[t0+2].x;
        o.y += cL[dy].y * wgt[t0].y + cC[dy].y * wgt[t0+1].y + cR[dy].y * wgt[t0+2].y;
        o.z += cL[dy].z * wgt[t0].z + cC[dy].z * wgt[t0+1].z + cR[dy].z * wgt[t0+2].z;
        o.w += cL[dy].w * wgt[t0].w + cC[dy].w * wgt[t0+1].w + cR[dy].w * wgt[t0+2].w;
      }
      // attention: Q[token, head hg] . Acol   (buffer row lr+1, swizzled)
      {
        const int br1 = lr + 1, sw = br1 & 7;
        const float* qb0 = &Qb[(br1 * 8 + wl) * 32];
        const float4 q0 = *reinterpret_cast<const float4*>(qb0 + (((hg*4+0)^sw)<<2));
        const float4 q1 = *reinterpret_cast<const float4*>(qb0 + (((hg*4+1)^sw)<<2));
        const float4 q2 = *reinterpret_cast<const float4*>(qb0 + (((hg*4+2)^sw)<<2));
        const float4 q3 = *reinterpret_cast<const float4*>(qb0 + (((hg*4+3)^sw)<<2));
        ACC(q0.x, 0)  ACC(q0.y, 1)  ACC(q0.z, 2)  ACC(q0.w, 3)
        ACC(q1.x, 4)  ACC(q1.y, 5)  ACC(q1.z, 6)  ACC(q1.w, 7)
        ACC(q2.x, 8)  ACC(q2.y, 9)  ACC(q2.z, 10) ACC(q2.w, 11)
        ACC(q3.x, 12) ACC(q3.y, 13) ACC(q3.z, 14) ACC(q3.w, 15)
      }
      float* dst = outp + win_base + (size_t)(r0 + lr) * (RES * DIM) +
                   wl * DIM + cg;
      *reinterpret_cast<float4*>(dst) = o;

#pragma unroll
      for (int dy = 0; dy < 3; ++dy) { cL[dy] = cC[dy]; cC[dy] = cR[dy]; }
    }
    __syncthreads();
    buf ^= 1;
  }
#undef ACC
}

// ---------------------------------------------------------------------------
extern "C" void kernel_launch(void* const* d_in, const int* in_sizes, int n_in,
                              void* d_out, int out_size, void* d_ws,
                              size_t ws_size, hipStream_t stream) {
  const float* qkv = (const float*)d_in[0];
  const float* cw  = (const float*)d_in[1];
  const float* cb  = (const float*)d_in[2];
  const float* Qg = qkv;
  const float* Kg = qkv + (size_t)BB * L * DIM;
  const float* Vg = Kg + (size_t)BB * L * DIM;
  float* outp = (float*)d_out;

  fused_lepe<<<512, 256, 0, stream>>>(Qg, Kg, Vg, cw, cb, outp);
}

// Round 6
// 61.203 us; speedup vs baseline: 1.1030x; 1.1030x over previous
//
#include <hip/hip_runtime.h>

// ---------------------------------------------------------------------------
// EfficentLePE, block-local: block = (window w, head-pair g).
// Window = [128 rows x 8 cols] tokens; head h <-> channels [h*16,(h+1)*16).
//   A[h] = softmax_e( SCALE * sum_n K[n,d] V[n,e] )   (16x16)
//   out[n,e] = sum_d Q[n,d] A[h][d,e] + depthwise3x3(Q)[n,e] + bias
// R4 structure; single change vs R4: pass-1 uses 8d x 4e register blocking
// (3 b128/lane per token-group vs 8 LDS instrs -> 2.7x fewer LDS issues)
// with shfl_xor(16/32) token-split pre-reduce into a 2KB scratch.
// ---------------------------------------------------------------------------

static constexpr int BB   = 8;
static constexpr int RES  = 128;
static constexpr int DIM  = 128;
static constexpr int WSP  = 8;
static constexpr int L    = RES * RES;   // 16384
static constexpr float SCALE = 0.25f;    // HD^-0.5, HD=16

#define GLD_LDS16(g, l)                                                        \
  __builtin_amdgcn_global_load_lds(                                            \
      (const __attribute__((address_space(1))) void*)(const void*)(g),         \
      (__attribute__((address_space(3))) void*)(l), 16, 0, 0)

__global__ __launch_bounds__(256, 2) void fused_lepe(
    const float* __restrict__ Qg, const float* __restrict__ Kg,
    const float* __restrict__ Vg, const float* __restrict__ cw,
    const float* __restrict__ cb, float* __restrict__ outp) {
  // smem map (floats):
  //  pass1: K dbuf [0,8192) (2 x 4096), V dbuf [8192,16384)
  //  scratch [0,2048)                  (after pass1; K0 dead)
  //  pass2: Qbuf0 [0,4608), Qbuf1 [4608,9216)
  //  A_sm  [16384,16896)
  __shared__ float smem[16896];
  float* const A_sm    = smem + 16384;
  float* const scratch = smem;

  const int b  = blockIdx.x;            // 0..511
  const int w  = b >> 2, g = b & 3;     // window, head-group (2 heads)
  const int bi = w >> 4, wb = w & 15;   // batch, window-col
  const int t  = threadIdx.x;
  const int wave = t >> 6, lane = t & 63;
  const size_t win_base = (size_t)(bi * L + wb * WSP) * DIM;
  const int ch0 = g * 32;               // first global channel of this group

  // ======== Pass 1: Gram = K^T V, 8 tiles of 16 image rows ================
  // lane = combo(4b) | split(2b): combo -> h1, dgrp (8-d group), eq (4-e quad)
  const int combo = lane & 15;
  const int split = lane >> 4;
  const int h1 = combo >> 3, dgrp = (combo >> 2) & 1, eq = combo & 3;
  const int koff = h1 * 16 + dgrp * 8;
  const int voff = h1 * 16 + eq * 4;
  const int n0 = (wave * 4 + split) * 8;   // 8 tokens per lane per tile

  float4 acc[8];
#pragma unroll
  for (int i = 0; i < 8; ++i) acc[i] = make_float4(0.f, 0.f, 0.f, 0.f);

  auto stageKV = [&](int tile, int buf) {
    // 32 chunks: mat (K/V) x 16 rows; 8 per wave. Chunk = 8 tokens x 32 ch.
    for (int c = wave; c < 32; c += 4) {
      const int mat = c >> 4, rr = c & 15;
      const int r = tile * 16 + rr;     // image row
      const float* src = (mat ? Vg : Kg) + win_base +
                         (size_t)r * (RES * DIM) + (lane >> 3) * DIM + ch0 +
                         (lane & 7) * 4;
      float* dst = smem + mat * 8192 + buf * 4096 + rr * 256;
      GLD_LDS16(src, dst);
    }
  };

  stageKV(0, 0);
  __syncthreads();
  for (int tt = 0; tt < 8; ++tt) {
    const int cur = tt & 1;
    if (tt < 7) stageKV(tt + 1, cur ^ 1);
    const float* Kb = smem + cur * 4096;
    const float* Vb = smem + 8192 + cur * 4096;
#pragma unroll 2
    for (int i = 0; i < 8; ++i) {
      const int n = n0 + i;
      const float4 k0 = *reinterpret_cast<const float4*>(&Kb[n * 32 + koff]);
      const float4 k1 = *reinterpret_cast<const float4*>(&Kb[n * 32 + koff + 4]);
      const float4 v  = *reinterpret_cast<const float4*>(&Vb[n * 32 + voff]);
#define FMA4(a, s)                                                             \
  a.x += (s) * v.x; a.y += (s) * v.y; a.z += (s) * v.z; a.w += (s) * v.w;
      FMA4(acc[0], k0.x) FMA4(acc[1], k0.y) FMA4(acc[2], k0.z) FMA4(acc[3], k0.w)
      FMA4(acc[4], k1.x) FMA4(acc[5], k1.y) FMA4(acc[6], k1.z) FMA4(acc[7], k1.w)
#undef FMA4
    }
    __syncthreads();
  }

  // within-wave reduce over the 4 token-splits (lane bits 4,5)
#pragma unroll
  for (int i = 0; i < 8; ++i) {
    acc[i].x += __shfl_xor(acc[i].x, 16); acc[i].y += __shfl_xor(acc[i].y, 16);
    acc[i].z += __shfl_xor(acc[i].z, 16); acc[i].w += __shfl_xor(acc[i].w, 16);
    acc[i].x += __shfl_xor(acc[i].x, 32); acc[i].y += __shfl_xor(acc[i].y, 32);
    acc[i].z += __shfl_xor(acc[i].z, 32); acc[i].w += __shfl_xor(acc[i].w, 32);
  }

  // ======== Q-tile staging helper (18 rows incl. halos, zero off-image) ===
  auto stageQ = [&](int tile, int buf) {
    const int r0 = tile * 16;
    float* qb = smem + buf * 4608;
    for (int c = wave; c < 18; c += 4) {
      const int r = r0 - 1 + c;         // image row for buffer row c
      float* dst = qb + c * 256;
      if ((unsigned)r < 128u) {
        const float* src = Qg + win_base + (size_t)r * (RES * DIM) +
                           (lane >> 3) * DIM + ch0 + (lane & 7) * 4;
        GLD_LDS16(src, dst);
      } else {
        *reinterpret_cast<float4*>(dst + lane * 4) =
            make_float4(0.f, 0.f, 0.f, 0.f);
      }
    }
  };

  // issue Q tile 0 into buf1 (latency hides under reduce below), then write
  // per-wave Gram partials -> scratch [wave][combo][8d*4e]
  stageQ(0, 1);
  if (lane < 16) {
    float* sc = scratch + wave * 512 + combo * 32;
#pragma unroll
    for (int i = 0; i < 8; ++i)
      *reinterpret_cast<float4*>(&sc[i * 4]) = acc[i];
  }
  __syncthreads();                       // scratch visible

  // ======== reduce 4 wave-copies + softmax over e -> A_sm[h*16+d][e] ======
  {
    const int r = t >> 3, e2 = t & 7;    // r = h*16+d, e in {2e2, 2e2+1}
    const int cmb = (r >> 4) * 8 + ((r >> 3) & 1) * 4 + (e2 >> 1);
    const float* s0 = scratch + cmb * 32 + (r & 7) * 4 + (e2 & 1) * 2;
    float v0 = (s0[0] + s0[512] + s0[1024] + s0[1536]) * SCALE;
    float v1 = (s0[1] + s0[513] + s0[1025] + s0[1537]) * SCALE;
    float m = fmaxf(v0, v1);
    m = fmaxf(m, __shfl_xor(m, 1));
    m = fmaxf(m, __shfl_xor(m, 2));
    m = fmaxf(m, __shfl_xor(m, 4));
    v0 = __expf(v0 - m); v1 = __expf(v1 - m);
    float ss = v0 + v1;
    ss += __shfl_xor(ss, 1);
    ss += __shfl_xor(ss, 2);
    ss += __shfl_xor(ss, 4);
    const float ri = 1.0f / ss;
    A_sm[r * 16 + e2 * 2 + 0] = v0 * ri;
    A_sm[r * 16 + e2 * 2 + 1] = v1 * ri;
  }
  __syncthreads();                       // A_sm ready; Q tile 0 drained

  // ======== Pass 2 setup: per-thread A column, conv weights, bias =========
  const int cq   = t & 7;                // channel quad (4 ch) within 32
  const int lr   = (t >> 3) & 15;        // local output row in tile
  const int half = t >> 7;               // wl range: half*4 .. half*4+3
  const int hg = cq >> 2, e0 = (cq & 3) * 4;
  const int cg = ch0 + cq * 4;           // global channel quad base

  float4 Acol[16];
#pragma unroll
  for (int d = 0; d < 16; ++d)
    Acol[d] = *reinterpret_cast<const float4*>(&A_sm[(hg * 16 + d) * 16 + e0]);
  float4 wgt[9];
#pragma unroll
  for (int tap = 0; tap < 9; ++tap) {
    wgt[tap].x = cw[(cg + 0) * 9 + tap];
    wgt[tap].y = cw[(cg + 1) * 9 + tap];
    wgt[tap].z = cw[(cg + 2) * 9 + tap];
    wgt[tap].w = cw[(cg + 3) * 9 + tap];
  }
  const float4 bias = *reinterpret_cast<const float4*>(&cb[cg]);
  const float4 zero4 = make_float4(0.f, 0.f, 0.f, 0.f);

#define ACC(qs, d)                                                             \
  o.x += (qs) * Acol[d].x; o.y += (qs) * Acol[d].y;                            \
  o.z += (qs) * Acol[d].z; o.w += (qs) * Acol[d].w;

  // ======== Pass 2 main loop: 8 tiles of 16 rows, double-buffered =========
  int buf = 1;
  for (int tile = 0; tile < 8; ++tile) {
    if (tile < 7) stageQ(tile + 1, buf ^ 1);
    const float* Qb = smem + buf * 4608;
    const int r0 = tile * 16;
    const int w0 = half * 4;

    float4 cL[3], cC[3], cR[3];
    auto ldcol = [&](int cidx, float4* dv) {
#pragma unroll
      for (int dy = 0; dy < 3; ++dy)
        dv[dy] = ((unsigned)cidx < 8u)
                     ? *reinterpret_cast<const float4*>(
                           &Qb[((lr + dy) * 8 + cidx) * 32 + cq * 4])
                     : zero4;
    };
    ldcol(w0 - 1, cL);
    ldcol(w0, cC);

#pragma unroll
    for (int k = 0; k < 4; ++k) {
      const int wl = w0 + k;
      ldcol(wl + 1, cR);
      float4 o = bias;
#pragma unroll
      for (int dy = 0; dy < 3; ++dy) {
        const int t0 = dy * 3;
        o.x += cL[dy].x * wgt[t0].x + cC[dy].x * wgt[t0+1].x + cR[dy].x * wgt[t0+2].x;
        o.y += cL[dy].y * wgt[t0].y + cC[dy].y * wgt[t0+1].y + cR[dy].y * wgt[t0+2].y;
        o.z += cL[dy].z * wgt[t0].z + cC[dy].z * wgt[t0+1].z + cR[dy].z * wgt[t0+2].z;
        o.w += cL[dy].w * wgt[t0].w + cC[dy].w * wgt[t0+1].w + cR[dy].w * wgt[t0+2].w;
      }
      // attention: Q[token, hg*16..+15] . Acol  (token buffer row = lr+1)
      const float* qr = &Qb[((lr + 1) * 8 + wl) * 32 + hg * 16];
      const float4 q0 = *reinterpret_cast<const float4*>(qr + 0);
      const float4 q1 = *reinterpret_cast<const float4*>(qr + 4);
      const float4 q2 = *reinterpret_cast<const float4*>(qr + 8);
      const float4 q3 = *reinterpret_cast<const float4*>(qr + 12);
      ACC(q0.x, 0)  ACC(q0.y, 1)  ACC(q0.z, 2)  ACC(q0.w, 3)
      ACC(q1.x, 4)  ACC(q1.y, 5)  ACC(q1.z, 6)  ACC(q1.w, 7)
      ACC(q2.x, 8)  ACC(q2.y, 9)  ACC(q2.z, 10) ACC(q2.w, 11)
      ACC(q3.x, 12) ACC(q3.y, 13) ACC(q3.z, 14) ACC(q3.w, 15)

      float* dst = outp + win_base + (size_t)(r0 + lr) * (RES * DIM) +
                   wl * DIM + cg;
      *reinterpret_cast<float4*>(dst) = o;

#pragma unroll
      for (int dy = 0; dy < 3; ++dy) { cL[dy] = cC[dy]; cC[dy] = cR[dy]; }
    }
    __syncthreads();
    buf ^= 1;
  }
#undef ACC
}

// ---------------------------------------------------------------------------
extern "C" void kernel_launch(void* const* d_in, const int* in_sizes, int n_in,
                              void* d_out, int out_size, void* d_ws,
                              size_t ws_size, hipStream_t stream) {
  const float* qkv = (const float*)d_in[0];
  const float* cw  = (const float*)d_in[1];
  const float* cb  = (const float*)d_in[2];
  const float* Qg = qkv;
  const float* Kg = qkv + (size_t)BB * L * DIM;
  const float* Vg = Kg + (size_t)BB * L * DIM;
  float* outp = (float*)d_out;

  fused_lepe<<<512, 256, 0, stream>>>(Qg, Kg, Vg, cw, cb, outp);
}

// Round 7
// 57.065 us; speedup vs baseline: 1.1830x; 1.0725x over previous
//
#include <hip/hip_runtime.h>

// ---------------------------------------------------------------------------
// EfficentLePE, block-local: block = (window w, head-pair g).
// Window = [128 rows x 8 cols] tokens; head h <-> channels [h*16,(h+1)*16).
//   A[h] = softmax_e( SCALE * sum_n K[n,d] V[n,e] )   (16x16)
//   out[n,e] = sum_d Q[n,d] A[h][d,e] + depthwise3x3(Q)[n,e] + bias
// R4 structure; single change vs R4: pass-1 uses 8d x 4e register blocking
// (3 b128/lane per token-group vs 8 LDS instrs -> 2.7x fewer LDS issues)
// with shfl_xor(16/32) token-split pre-reduce into a 2KB scratch.
// ---------------------------------------------------------------------------

static constexpr int BB   = 8;
static constexpr int RES  = 128;
static constexpr int DIM  = 128;
static constexpr int WSP  = 8;
static constexpr int L    = RES * RES;   // 16384
static constexpr float SCALE = 0.25f;    // HD^-0.5, HD=16

#define GLD_LDS16(g, l)                                                        \
  __builtin_amdgcn_global_load_lds(                                            \
      (const __attribute__((address_space(1))) void*)(const void*)(g),         \
      (__attribute__((address_space(3))) void*)(l), 16, 0, 0)

__global__ __launch_bounds__(256, 2) void fused_lepe(
    const float* __restrict__ Qg, const float* __restrict__ Kg,
    const float* __restrict__ Vg, const float* __restrict__ cw,
    const float* __restrict__ cb, float* __restrict__ outp) {
  // smem map (floats):
  //  pass1: K dbuf [0,8192) (2 x 4096), V dbuf [8192,16384)
  //  scratch [0,2048)                  (after pass1; K0 dead)
  //  pass2: Qbuf0 [0,4608), Qbuf1 [4608,9216)
  //  A_sm  [16384,16896)
  __shared__ float smem[16896];
  float* const A_sm    = smem + 16384;
  float* const scratch = smem;

  const int b  = blockIdx.x;            // 0..511
  const int w  = b >> 2, g = b & 3;     // window, head-group (2 heads)
  const int bi = w >> 4, wb = w & 15;   // batch, window-col
  const int t  = threadIdx.x;
  const int wave = t >> 6, lane = t & 63;
  const size_t win_base = (size_t)(bi * L + wb * WSP) * DIM;
  const int ch0 = g * 32;               // first global channel of this group

  // ======== Pass 1: Gram = K^T V, 8 tiles of 16 image rows ================
  // lane = combo(4b) | split(2b): combo -> h1, dgrp (8-d group), eq (4-e quad)
  const int combo = lane & 15;
  const int split = lane >> 4;
  const int h1 = combo >> 3, dgrp = (combo >> 2) & 1, eq = combo & 3;
  const int koff = h1 * 16 + dgrp * 8;
  const int voff = h1 * 16 + eq * 4;
  const int n0 = (wave * 4 + split) * 8;   // 8 tokens per lane per tile

  float4 acc[8];
#pragma unroll
  for (int i = 0; i < 8; ++i) acc[i] = make_float4(0.f, 0.f, 0.f, 0.f);

  auto stageKV = [&](int tile, int buf) {
    // 32 chunks: mat (K/V) x 16 rows; 8 per wave. Chunk = 8 tokens x 32 ch.
    for (int c = wave; c < 32; c += 4) {
      const int mat = c >> 4, rr = c & 15;
      const int r = tile * 16 + rr;     // image row
      const float* src = (mat ? Vg : Kg) + win_base +
                         (size_t)r * (RES * DIM) + (lane >> 3) * DIM + ch0 +
                         (lane & 7) * 4;
      float* dst = smem + mat * 8192 + buf * 4096 + rr * 256;
      GLD_LDS16(src, dst);
    }
  };

  stageKV(0, 0);
  __syncthreads();
  for (int tt = 0; tt < 8; ++tt) {
    const int cur = tt & 1;
    if (tt < 7) stageKV(tt + 1, cur ^ 1);
    const float* Kb = smem + cur * 4096;
    const float* Vb = smem + 8192 + cur * 4096;
#pragma unroll 2
    for (int i = 0; i < 8; ++i) {
      const int n = n0 + i;
      const float4 k0 = *reinterpret_cast<const float4*>(&Kb[n * 32 + koff]);
      const float4 k1 = *reinterpret_cast<const float4*>(&Kb[n * 32 + koff + 4]);
      const float4 v  = *reinterpret_cast<const float4*>(&Vb[n * 32 + voff]);
#define FMA4(a, s)                                                             \
  a.x += (s) * v.x; a.y += (s) * v.y; a.z += (s) * v.z; a.w += (s) * v.w;
      FMA4(acc[0], k0.x) FMA4(acc[1], k0.y) FMA4(acc[2], k0.z) FMA4(acc[3], k0.w)
      FMA4(acc[4], k1.x) FMA4(acc[5], k1.y) FMA4(acc[6], k1.z) FMA4(acc[7], k1.w)
#undef FMA4
    }
    __syncthreads();
  }

  // within-wave reduce over the 4 token-splits (lane bits 4,5)
#pragma unroll
  for (int i = 0; i < 8; ++i) {
    acc[i].x += __shfl_xor(acc[i].x, 16); acc[i].y += __shfl_xor(acc[i].y, 16);
    acc[i].z += __shfl_xor(acc[i].z, 16); acc[i].w += __shfl_xor(acc[i].w, 16);
    acc[i].x += __shfl_xor(acc[i].x, 32); acc[i].y += __shfl_xor(acc[i].y, 32);
    acc[i].z += __shfl_xor(acc[i].z, 32); acc[i].w += __shfl_xor(acc[i].w, 32);
  }

  // ======== Q-tile staging helper (18 rows incl. halos, zero off-image) ===
  auto stageQ = [&](int tile, int buf) {
    const int r0 = tile * 16;
    float* qb = smem + buf * 4608;
    for (int c = wave; c < 18; c += 4) {
      const int r = r0 - 1 + c;         // image row for buffer row c
      float* dst = qb + c * 256;
      if ((unsigned)r < 128u) {
        const float* src = Qg + win_base + (size_t)r * (RES * DIM) +
                           (lane >> 3) * DIM + ch0 + (lane & 7) * 4;
        GLD_LDS16(src, dst);
      } else {
        *reinterpret_cast<float4*>(dst + lane * 4) =
            make_float4(0.f, 0.f, 0.f, 0.f);
      }
    }
  };

  // issue Q tile 0 into buf1 (latency hides under reduce below), then write
  // per-wave Gram partials -> scratch [wave][combo][8d*4e]
  stageQ(0, 1);
  if (lane < 16) {
    float* sc = scratch + wave * 512 + combo * 32;
#pragma unroll
    for (int i = 0; i < 8; ++i)
      *reinterpret_cast<float4*>(&sc[i * 4]) = acc[i];
  }
  __syncthreads();                       // scratch visible

  // ======== reduce 4 wave-copies + softmax over e -> A_sm[h*16+d][e] ======
  {
    const int r = t >> 3, e2 = t & 7;    // r = h*16+d, e in {2e2, 2e2+1}
    const int cmb = (r >> 4) * 8 + ((r >> 3) & 1) * 4 + (e2 >> 1);
    const float* s0 = scratch + cmb * 32 + (r & 7) * 4 + (e2 & 1) * 2;
    float v0 = (s0[0] + s0[512] + s0[1024] + s0[1536]) * SCALE;
    float v1 = (s0[1] + s0[513] + s0[1025] + s0[1537]) * SCALE;
    float m = fmaxf(v0, v1);
    m = fmaxf(m, __shfl_xor(m, 1));
    m = fmaxf(m, __shfl_xor(m, 2));
    m = fmaxf(m, __shfl_xor(m, 4));
    v0 = __expf(v0 - m); v1 = __expf(v1 - m);
    float ss = v0 + v1;
    ss += __shfl_xor(ss, 1);
    ss += __shfl_xor(ss, 2);
    ss += __shfl_xor(ss, 4);
    const float ri = 1.0f / ss;
    A_sm[r * 16 + e2 * 2 + 0] = v0 * ri;
    A_sm[r * 16 + e2 * 2 + 1] = v1 * ri;
  }
  __syncthreads();                       // A_sm ready; Q tile 0 drained

  // ======== Pass 2 setup: per-thread A column, conv weights, bias =========
  const int cq   = t & 7;                // channel quad (4 ch) within 32
  const int lr   = (t >> 3) & 15;        // local output row in tile
  const int half = t >> 7;               // wl range: half*4 .. half*4+3
  const int hg = cq >> 2, e0 = (cq & 3) * 4;
  const int cg = ch0 + cq * 4;           // global channel quad base

  float4 Acol[16];
#pragma unroll
  for (int d = 0; d < 16; ++d)
    Acol[d] = *reinterpret_cast<const float4*>(&A_sm[(hg * 16 + d) * 16 + e0]);
  float4 wgt[9];
#pragma unroll
  for (int tap = 0; tap < 9; ++tap) {
    wgt[tap].x = cw[(cg + 0) * 9 + tap];
    wgt[tap].y = cw[(cg + 1) * 9 + tap];
    wgt[tap].z = cw[(cg + 2) * 9 + tap];
    wgt[tap].w = cw[(cg + 3) * 9 + tap];
  }
  const float4 bias = *reinterpret_cast<const float4*>(&cb[cg]);
  const float4 zero4 = make_float4(0.f, 0.f, 0.f, 0.f);

#define ACC(qs, d)                                                             \
  o.x += (qs) * Acol[d].x; o.y += (qs) * Acol[d].y;                            \
  o.z += (qs) * Acol[d].z; o.w += (qs) * Acol[d].w;

  // ======== Pass 2 main loop: 8 tiles of 16 rows, double-buffered =========
  int buf = 1;
  for (int tile = 0; tile < 8; ++tile) {
    if (tile < 7) stageQ(tile + 1, buf ^ 1);
    const float* Qb = smem + buf * 4608;
    const int r0 = tile * 16;
    const int w0 = half * 4;

    float4 cL[3], cC[3], cR[3];
    auto ldcol = [&](int cidx, float4* dv) {
#pragma unroll
      for (int dy = 0; dy < 3; ++dy)
        dv[dy] = ((unsigned)cidx < 8u)
                     ? *reinterpret_cast<const float4*>(
                           &Qb[((lr + dy) * 8 + cidx) * 32 + cq * 4])
                     : zero4;
    };
    ldcol(w0 - 1, cL);
    ldcol(w0, cC);

#pragma unroll
    for (int k = 0; k < 4; ++k) {
      const int wl = w0 + k;
      ldcol(wl + 1, cR);
      float4 o = bias;
#pragma unroll
      for (int dy = 0; dy < 3; ++dy) {
        const int t0 = dy * 3;
        o.x += cL[dy].x * wgt[t0].x + cC[dy].x * wgt[t0+1].x + cR[dy].x * wgt[t0+2].x;
        o.y += cL[dy].y * wgt[t0].y + cC[dy].y * wgt[t0+1].y + cR[dy].y * wgt[t0+2].y;
        o.z += cL[dy].z * wgt[t0].z + cC[dy].z * wgt[t0+1].z + cR[dy].z * wgt[t0+2].z;
        o.w += cL[dy].w * wgt[t0].w + cC[dy].w * wgt[t0+1].w + cR[dy].w * wgt[t0+2].w;
      }
      // attention: Q[token, hg*16..+15] . Acol  (token buffer row = lr+1)
      const float* qr = &Qb[((lr + 1) * 8 + wl) * 32 + hg * 16];
      const float4 q0 = *reinterpret_cast<const float4*>(qr + 0);
      const float4 q1 = *reinterpret_cast<const float4*>(qr + 4);
      const float4 q2 = *reinterpret_cast<const float4*>(qr + 8);
      const float4 q3 = *reinterpret_cast<const float4*>(qr + 12);
      ACC(q0.x, 0)  ACC(q0.y, 1)  ACC(q0.z, 2)  ACC(q0.w, 3)
      ACC(q1.x, 4)  ACC(q1.y, 5)  ACC(q1.z, 6)  ACC(q1.w, 7)
      ACC(q2.x, 8)  ACC(q2.y, 9)  ACC(q2.z, 10) ACC(q2.w, 11)
      ACC(q3.x, 12) ACC(q3.y, 13) ACC(q3.z, 14) ACC(q3.w, 15)

      float* dst = outp + win_base + (size_t)(r0 + lr) * (RES * DIM) +
                   wl * DIM + cg;
      *reinterpret_cast<float4*>(dst) = o;

#pragma unroll
      for (int dy = 0; dy < 3; ++dy) { cL[dy] = cC[dy]; cC[dy] = cR[dy]; }
    }
    __syncthreads();
    buf ^= 1;
  }
#undef ACC
}

// ---------------------------------------------------------------------------
extern "C" void kernel_launch(void* const* d_in, const int* in_sizes, int n_in,
                              void* d_out, int out_size, void* d_ws,
                              size_t ws_size, hipStream_t stream) {
  const float* qkv = (const float*)d_in[0];
  const float* cw  = (const float*)d_in[1];
  const float* cb  = (const float*)d_in[2];
  const float* Qg = qkv;
  const float* Kg = qkv + (size_t)BB * L * DIM;
  const float* Vg = Kg + (size_t)BB * L * DIM;
  float* outp = (float*)d_out;

  fused_lepe<<<512, 256, 0, stream>>>(Qg, Kg, Vg, cw, cb, outp);
}